// Round 1
// baseline (306.574 us; speedup 1.0000x reference)
//
#include <hip/hip_runtime.h>
#include <cfloat>

#define NROWS  32768
#define NCODES 8192
#define DDIM   256
#define KG     2                 // code-split; grid = 128 row-tiles * 2 = 256 blocks
#define CPB    (NCODES / KG)     // 4096 codes per block
#define CT     64                // codes per stage/tile (32 KB) -- 3-buffer pipeline
#define TPB    (CPB / CT)        // 64 stages per block

typedef __attribute__((ext_vector_type(8))) __bf16 bf16x8;
typedef __attribute__((ext_vector_type(4))) float  f32x4;

// ---- kernel A: codebook fp32 -> bf16 + fused esq ----
__global__ __launch_bounds__(256)
void cvt_cb(const float* __restrict__ cb, __bf16* __restrict__ cbb,
            float* __restrict__ esq) {
    const size_t i = (size_t)(blockIdx.x * 256 + threadIdx.x) * 8;
    const float4 f0 = *(const float4*)(cb + i);
    const float4 f1 = *(const float4*)(cb + i + 4);
    bf16x8 v;
    v[0] = (__bf16)f0.x; v[1] = (__bf16)f0.y; v[2] = (__bf16)f0.z; v[3] = (__bf16)f0.w;
    v[4] = (__bf16)f1.x; v[5] = (__bf16)f1.y; v[6] = (__bf16)f1.z; v[7] = (__bf16)f1.w;
    *(bf16x8*)(cbb + i) = v;
    float s = f0.x * f0.x + f0.y * f0.y + f0.z * f0.z + f0.w * f0.w
            + f1.x * f1.x + f1.y * f1.y + f1.z * f1.z + f1.w * f1.w;
    for (int o = 16; o > 0; o >>= 1) s += __shfl_down(s, o, 32);
    if ((threadIdx.x & 31) == 0) esq[i >> 8] = s;
}

// ---- kernel B: A-in-regs, 256 rows/block, counted-vmcnt 3-buffer pipeline ----
// 512 thr / 8 waves (4 row-groups x 2 col-groups). A: 64 rows x 256 k per wave
// in VGPRs (-2*z). B: 64-code x 256-k tiles (32 KB) staged via global_load_lds
// into a 3-deep ring; prefetch distance 2. Main loop NEVER drains vmcnt to 0:
// per stage issue 4 loads for t+2, compute t, then `s_waitcnt vmcnt(4)` (waits
// only t+1's loads; t+2's stay in flight across the raw s_barrier). esq lives
// in LDS so no global loads pollute the vmcnt counting inside the loop.
// Barrier sits BEFORE the register-only argmin tail so argmin overlaps other
// waves' next-stage MFMAs. setprio(1) around the MFMA cluster (T5).
__global__ __launch_bounds__(512, 2)
void vq_mfma(const float* __restrict__ z, const __bf16* __restrict__ cbb,
             const float* __restrict__ esq,
             float* __restrict__ pV, int* __restrict__ pI) {
    __shared__ __align__(16) __bf16 Bb[3][CT * DDIM];   // 3 x 32 KB ring
    __shared__ __align__(16) float  esqLds[CPB];        // 16 KB
    __shared__ float RedV[256][2];
    __shared__ int   RedI[256][2];

    const int rowbase  = (blockIdx.x >> 1) * 256;
    const int kg       = blockIdx.x & 1;
    const int codebase = kg * CPB;

    const int tid = threadIdx.x;
    const int w = tid >> 6, l = tid & 63;
    const int rh = w >> 1, ch = w & 1;     // 4 row-groups x 2 col-groups
    const int lm = l & 15, lq = l >> 4;
    const int loff = lm * DDIM + lq * 8;   // lane offset within a 16-code group
    // staging role: wave w stages code-group g (16 codes) x k-chunks jbase..+3
    const int g = w & 3, jbase = (w >> 2) * 4;

    // ---- prologue: issue stages 0 and 1 into ring slots 0/1 ----
#pragma unroll
    for (int s0 = 0; s0 < 2; ++s0) {
        const __bf16* src = cbb + (size_t)(codebase + s0 * CT + g * 16) * DDIM;
#pragma unroll
        for (int jj = 0; jj < 4; ++jj) {
            const int j = jbase + jj;
            __builtin_amdgcn_global_load_lds(
                (const __attribute__((address_space(1))) void*)(src + j * 32 + loff),
                (__attribute__((address_space(3))) void*)(&Bb[s0][(j * 4 + g) * 512]),
                16, 0, 0);
        }
    }

    // ---- esq -> LDS once (4096 floats; 8 per thread) ----
    {
        const float4 q0 = *(const float4*)(esq + codebase + tid * 8);
        const float4 q1 = *(const float4*)(esq + codebase + tid * 8 + 4);
        *(float4*)&esqLds[tid * 8]     = q0;
        *(float4*)&esqLds[tid * 8 + 4] = q1;
    }

    // ---- A prologue: 64 rows x 256 k per wave -> 32 bf16x8 frags (-2*z) ----
    bf16x8 Af[4][8];   // [row-seg fr][k-chunk]
    {
        const float* zp = z + (size_t)(rowbase + rh * 64 + lm) * DDIM + lq * 8;
#pragma unroll
        for (int s = 0; s < 4; ++s)
#pragma unroll
            for (int kc = 0; kc < 8; ++kc) {
                const float4 f0 = *(const float4*)(zp + s * 16 * DDIM + kc * 32);
                const float4 f1 = *(const float4*)(zp + s * 16 * DDIM + kc * 32 + 4);
                bf16x8 v;
                v[0] = (__bf16)(-2.f * f0.x); v[1] = (__bf16)(-2.f * f0.y);
                v[2] = (__bf16)(-2.f * f0.z); v[3] = (__bf16)(-2.f * f0.w);
                v[4] = (__bf16)(-2.f * f1.x); v[5] = (__bf16)(-2.f * f1.y);
                v[6] = (__bf16)(-2.f * f1.z); v[7] = (__bf16)(-2.f * f1.w);
                Af[s][kc] = v;
            }
    }

    float bestV[16];
    int   bestI[16];
#pragma unroll
    for (int s = 0; s < 16; ++s) { bestV[s] = FLT_MAX; bestI[s] = 0; }

    // one full drain at the prologue only: stage 0/1 + A-loads + esq writes
    asm volatile("s_waitcnt vmcnt(0) lgkmcnt(0)" ::: "memory");
    __builtin_amdgcn_s_barrier();

    unsigned bc = 0, bn = 1, bp = 2;   // ring: current / next / prefetch-dest
#pragma unroll 1
    for (int t = 0; t < TPB; ++t) {
        // issue stage t+2 into slot bp (its readers retired at barrier t-1)
        if (t + 2 < TPB) {
            const __bf16* src = cbb + (size_t)(codebase + (t + 2) * CT + g * 16) * DDIM;
#pragma unroll
            for (int jj = 0; jj < 4; ++jj) {
                const int j = jbase + jj;
                __builtin_amdgcn_global_load_lds(
                    (const __attribute__((address_space(1))) void*)(src + j * 32 + loff),
                    (__attribute__((address_space(3))) void*)(&Bb[bp][(j * 4 + g) * 512]),
                    16, 0, 0);
            }
        }

        // acc init = esq broadcast (LDS; lgkm-tracked, keeps vmcnt clean)
        const float e0 = esqLds[t * CT + ch * 32 + lm];
        const float e1 = esqLds[t * CT + ch * 32 + 16 + lm];
        f32x4 acc[4][2];
#pragma unroll
        for (int fr = 0; fr < 4; ++fr) {
            acc[fr][0] = (f32x4){e0, e0, e0, e0};
            acc[fr][1] = (f32x4){e1, e1, e1, e1};
        }

        const __bf16* Bc = &Bb[bc][0];
        __builtin_amdgcn_s_setprio(1);
#pragma unroll
        for (int c = 0; c < 8; ++c) {
            const bf16x8 b0 = *(const bf16x8*)(Bc + (c * 4 + ch * 2 + 0) * 512 + l * 8);
            const bf16x8 b1 = *(const bf16x8*)(Bc + (c * 4 + ch * 2 + 1) * 512 + l * 8);
#pragma unroll
            for (int fr = 0; fr < 4; ++fr)
                acc[fr][0] = __builtin_amdgcn_mfma_f32_16x16x32_bf16(
                    Af[fr][c], b0, acc[fr][0], 0, 0, 0);
#pragma unroll
            for (int fr = 0; fr < 4; ++fr)
                acc[fr][1] = __builtin_amdgcn_mfma_f32_16x16x32_bf16(
                    Af[fr][c], b1, acc[fr][1], 0, 0, 0);
        }
        __builtin_amdgcn_s_setprio(0);

        // counted wait: t+1's 4 loads (issued last iter) must be done; t+2's
        // 4 stay in flight ACROSS the barrier. lgkmcnt(0) closes the WAR
        // window on this wave's in-flight ds_reads of Bb[bc].
        if (t + 1 < TPB) {
            if (t + 2 < TPB)
                asm volatile("s_waitcnt vmcnt(4) lgkmcnt(0)" ::: "memory");
            else
                asm volatile("s_waitcnt vmcnt(0) lgkmcnt(0)" ::: "memory");
            __builtin_amdgcn_s_barrier();
        }

        // fused argmin on registers (overlaps other waves' next stage).
        // tiles ascend; fc ascend = cols ascend; strict < keeps smallest idx
        const int colBase = codebase + t * CT + ch * 32 + lm;
#pragma unroll
        for (int fr = 0; fr < 4; ++fr)
#pragma unroll
            for (int fc = 0; fc < 2; ++fc) {
                const int colI = colBase + fc * 16;
#pragma unroll
                for (int i = 0; i < 4; ++i) {
                    const float sc = acc[fr][fc][i];
                    const int slot = fr * 4 + i;
                    if (sc < bestV[slot]) { bestV[slot] = sc; bestI[slot] = colI; }
                }
            }

        const unsigned tmp = bc; bc = bn; bn = bp; bp = tmp;
    }

    // cross-lane argmin over the 16 col-lanes (lane bits 0..3 = lm)
#pragma unroll
    for (int s = 0; s < 16; ++s) {
#pragma unroll
        for (int m = 1; m < 16; m <<= 1) {
            const float v2 = __shfl_xor(bestV[s], m);
            const int   i2 = __shfl_xor(bestI[s], m);
            if (v2 < bestV[s] || (v2 == bestV[s] && i2 < bestI[s])) {
                bestV[s] = v2; bestI[s] = i2;
            }
        }
    }
    if (lm == 0) {
#pragma unroll
        for (int s = 0; s < 16; ++s) {   // row = rh*64 + fr*16 + lq*4 + i
            const int rl = rh * 64 + (s >> 2) * 16 + lq * 4 + (s & 3);
            RedV[rl][ch] = bestV[s]; RedI[rl][ch] = bestI[s];
        }
    }
    __syncthreads();
    if (tid < 256) {  // combine the two col-halves; tie -> smaller index
        float v = RedV[tid][0]; int bi = RedI[tid][0];
        const float v2 = RedV[tid][1]; const int i2 = RedI[tid][1];
        if (v2 < v || (v2 == v && i2 < bi)) { v = v2; bi = i2; }
        const int row = rowbase + tid;
        pV[row * KG + kg] = v; pI[row * KG + kg] = bi;
    }
}

// ---- kernel C: combine K-groups, gather (fp32), STE out, loss partials ----
__global__ __launch_bounds__(256)
void vq_finalize(const float* __restrict__ z, const float* __restrict__ cb,
                 const float* __restrict__ pV, const int* __restrict__ pI,
                 float* __restrict__ out, float* __restrict__ bsum) {
    __shared__ float sSum[4];
    __shared__ int   sIdx[4];
    const int tid = threadIdx.x;
    const int rw = tid >> 6, lane = tid & 63;
    const int row = blockIdx.x * 4 + rw;

    if (lane == 0) {  // ascending kg = ascending index; strict < keeps first
        float v = pV[row * KG]; int bi = pI[row * KG];
        const float v2 = pV[row * KG + 1]; const int i2 = pI[row * KG + 1];
        if (v2 < v || (v2 == v && i2 < bi)) { v = v2; bi = i2; }
        sIdx[rw] = bi;
    }
    __syncthreads();
    const int idx = sIdx[rw];

    const float4 zv = *(const float4*)(z  + (size_t)row * DDIM + lane * 4);
    const float4 ev = *(const float4*)(cb + (size_t)idx * DDIM + lane * 4);
    float4 d, o;
    d.x = ev.x - zv.x; d.y = ev.y - zv.y; d.z = ev.z - zv.z; d.w = ev.w - zv.w;
    o.x = zv.x + d.x;  o.y = zv.y + d.y;  o.z = zv.z + d.z;  o.w = zv.w + d.w;
    *(float4*)(out + (size_t)row * DDIM + lane * 4) = o;

    float s = d.x * d.x + d.y * d.y + d.z * d.z + d.w * d.w;
    for (int off = 32; off > 0; off >>= 1) s += __shfl_down(s, off);
    if (lane == 0) sSum[rw] = s;
    __syncthreads();
    if (tid == 0) bsum[blockIdx.x] = sSum[0] + sSum[1] + sSum[2] + sSum[3];
}

// ---- kernel D: loss ----
__global__ __launch_bounds__(256)
void loss_final(const float* __restrict__ bsum, float* __restrict__ out) {
    __shared__ float red[4];
    const int tid = threadIdx.x;
    float s = 0.f;
    for (int i = tid; i < NROWS / 4; i += 256) s += bsum[i];
    for (int off = 32; off > 0; off >>= 1) s += __shfl_down(s, off);
    const int wv = tid >> 6, lane = tid & 63;
    if (lane == 0) red[wv] = s;
    __syncthreads();
    if (tid == 0) {
        const float tot = red[0] + red[1] + red[2] + red[3];
        out[(size_t)NROWS * DDIM] = tot * (1.25f / (float)((size_t)NROWS * DDIM));
    }
}

extern "C" void kernel_launch(void* const* d_in, const int* in_sizes, int n_in,
                              void* d_out, int out_size, void* d_ws, size_t ws_size,
                              hipStream_t stream) {
    const float* z  = (const float*)d_in[0];
    const float* cb = (const float*)d_in[1];
    float* out = (float*)d_out;

    // bf16 codebook staged at head of d_out (4 MB; consumed by vq_mfma
    // before vq_finalize overwrites the region)
    __bf16* cbf = (__bf16*)d_out;

    // workspace carve (~580 KB)
    float* esq  = (float*)d_ws;                 // 8192
    float* pV   = esq + NCODES;                 // 32768*2
    int*   pI   = (int*)(pV + NROWS * KG);      // 32768*2
    float* bsum = (float*)(pI + NROWS * KG);    // 8192

    cvt_cb<<<NCODES * DDIM / 8 / 256, 256, 0, stream>>>(cb, cbf, esq);
    vq_mfma<<<(NROWS / 256) * KG, 512, 0, stream>>>(z, cbf, esq, pV, pI);
    vq_finalize<<<NROWS / 4, 256, 0, stream>>>(z, cb, pV, pI, out, bsum);
    loss_final<<<1, 256, 0, stream>>>(bsum, out);
}